// Round 13
// baseline (107.107 us; speedup 1.0000x reference)
//
#include <hip/hip_runtime.h>

// ConvAutoEncoder: B=16384, T=64, C=2, D=4
// out = [encoder_out (B*128 f32) | decoded (B*128 f32)]
// R7 kernel (best: 50.6us) as k_fused<0> + two DIAGNOSTIC dispatches into d_ws:
//   k_fused<1> = attention phase only   -> diag_h
//   k_fused<2> = MFMA phases only       -> diag_enc/diag_dec (synthetic h)
// rocprof reports each dispatch separately -> per-phase timing.

typedef __attribute__((ext_vector_type(8))) short bf16x8;
typedef __attribute__((ext_vector_type(4))) float f32x4;

__device__ __forceinline__ unsigned short f2bf(float f) {
    unsigned int u = __builtin_bit_cast(unsigned int, f);
    return (unsigned short)((u + 0x7FFFu + ((u >> 16) & 1u)) >> 16);
}
__device__ __forceinline__ unsigned int pack2bf(float a, float b) {
    return (unsigned int)f2bf(a) | ((unsigned int)f2bf(b) << 16);
}

#define SWZ(row) (((row) & 7) << 3)   // ushort-index XOR == byte XOR ((row&7)<<4)

// ---------------- kernel 0: weight prep ----------------
__global__ void k0_prep(const float* __restrict__ w1, const float* __restrict__ w2,
                        const float* __restrict__ cw, const float* __restrict__ cb,
                        unsigned short* __restrict__ w1b, unsigned short* __restrict__ w2b,
                        unsigned short* __restrict__ wcv, float* __restrict__ biasf) {
    int i = blockIdx.x * 256 + threadIdx.x;      // 0..65535
    if (i < 512 * 128) { w1b[i] = f2bf(w1[i]); w2b[i] = f2bf(w2[i]); }
    if (i < 128 * 256) {
        int f = i >> 8, kd = i & 255;            // f = 2*o + s, kd = node*4 + d
        int o = f >> 1, s = f & 1, node = kd >> 2, d = kd & 3;
        int k = d - s;
        float v = (k >= 0 && k < 3) ? cw[o * 192 + node * 3 + k] : 0.f;
        wcv[i] = f2bf(v);
    }
    if (i < 128) biasf[i] = cb[i >> 1];
}

// ---------------- fused kernel (R7 structure), MODE-parameterized ----------------
// MODE 0: full (real outputs). MODE 1: attention only -> diag_h, early return.
// MODE 2: skip attention (synthetic h_lds), MFMA phases -> diag_enc/diag_dec.
template<int MODE>
__global__ __launch_bounds__(256, 4) void k_fused(
    const float* __restrict__ x,             // (B,64,2)
    const float* __restrict__ W_gat,         // (4,2)
    const float* __restrict__ a_attn,        // (8,)
    const unsigned short* __restrict__ w1b,  // (512,128)
    const unsigned short* __restrict__ w2b,  // (128,512)
    const unsigned short* __restrict__ wcv,  // (128,256)
    const float* __restrict__ biasf,         // (128,)
    const float* __restrict__ b1,            // (512,)
    const float* __restrict__ b2,            // (128,)
    float* __restrict__ enc_out,             // (B,128) f32 (or diag)
    float* __restrict__ dec_out,             // (B,128) f32 (or diag)
    uint2* __restrict__ diag_h)              // (B,64) diag h sink (MODE 1)
{
    __shared__ __align__(16) unsigned char smem[28672];
    unsigned short* h_lds    = (unsigned short*)smem;            // [16][256] bf16 swz, 8KB
    unsigned short* flat_lds = (unsigned short*)(smem + 8192);   // [16][128] bf16 swz, 4KB
    float*          scr      = (float*)(smem + 12288);           // [4 waves][4 rows][4][64], 16KB } aliased
    unsigned short* hdec_lds = (unsigned short*)(smem + 12288);  // [16][512] bf16 swz, 16KB      }

    const int tid = threadIdx.x, lane = tid & 63, wv = tid >> 6;  // wv 0..3
    const int r = lane & 15, g = lane >> 4;
    const int base = blockIdx.x * 16;

    // ================= attention (4 rows per wave) =================
    if (MODE != 2) {
        const float Wg00 = W_gat[0], Wg01 = W_gat[1], Wg10 = W_gat[2], Wg11 = W_gat[3];
        const float Wg20 = W_gat[4], Wg21 = W_gat[5], Wg30 = W_gat[6], Wg31 = W_gat[7];
        const float as0 = a_attn[0], as1 = a_attn[1], as2 = a_attn[2], as3 = a_attn[3];
        const float ad0 = a_attn[4], ad1 = a_attn[5], ad2 = a_attn[6], ad3 = a_attn[7];
        const float cs0 = as0 * Wg00 + as1 * Wg10 + as2 * Wg20 + as3 * Wg30;
        const float cs1 = as0 * Wg01 + as1 * Wg11 + as2 * Wg21 + as3 * Wg31;
        const float cd0 = ad0 * Wg00 + ad1 * Wg10 + ad2 * Wg20 + ad3 * Wg30;
        const float cd1 = ad0 * Wg01 + ad1 * Wg11 + ad2 * Wg21 + ad3 * Wg31;
        const float L2E = 1.4426950408889634f;
        const float SL = 0.2f;

        float* wbuf = scr + wv * 1024;       // 4 rows x 256 floats (x0|x1|u|v)
        float x0s[4], x1s[4], us[4], vs[4], Us[4], Vs[4];

        #pragma unroll
        for (int t = 0; t < 4; ++t) {
            const float2 xv = ((const float2*)x)[(size_t)(base + wv * 4 + t) * 64 + lane];
            const float x0 = xv.x, x1 = xv.y;
            const float es = x0 * cs0 + x1 * cs1;
            const float ed = x0 * cd0 + x1 * cd1;
            const float u = __builtin_amdgcn_exp2f(es * L2E);         // e^{es}
            const float v = __builtin_amdgcn_exp2f(es * (SL * L2E));  // e^{0.2 es}
            const float U = __builtin_amdgcn_exp2f(ed * L2E);
            const float V = __builtin_amdgcn_exp2f(ed * (SL * L2E));
            float* Bf = wbuf + t * 256;
            Bf[lane] = x0; Bf[64 + lane] = x1; Bf[128 + lane] = u; Bf[192 + lane] = v;
            x0s[t] = x0; x1s[t] = x1; us[t] = u; vs[t] = v; Us[t] = U; Vs[t] = V;
        }

        #pragma unroll
        for (int tp = 0; tp < 2; ++tp) {      // two rows interleaved
            const int ta = tp * 2, tb = ta + 1;
            const float* Ba = wbuf + ta * 256;
            const float* Bb = wbuf + tb * 256;
            const f32x4 Ua4 = {Us[ta], Us[ta], Us[ta], Us[ta]};
            const f32x4 Va4 = {Vs[ta], Vs[ta], Vs[ta], Vs[ta]};
            const f32x4 Ub4 = {Us[tb], Us[tb], Us[tb], Us[tb]};
            const f32x4 Vb4 = {Vs[tb], Vs[tb], Vs[tb], Vs[tb]};
            f32x4 Sa = {0.f, 0.f, 0.f, 0.f}, A0a = Sa, A1a = Sa;
            f32x4 Sb = Sa, A0b = Sa, A1b = Sa;
            #pragma unroll
            for (int i4 = 0; i4 < 16; ++i4) {
                const f32x4 ax0 = *(const f32x4*)(Ba + i4 * 4);
                const f32x4 ax1 = *(const f32x4*)(Ba + 64 + i4 * 4);
                const f32x4 au  = *(const f32x4*)(Ba + 128 + i4 * 4);
                const f32x4 av  = *(const f32x4*)(Ba + 192 + i4 * 4);
                const f32x4 bx0 = *(const f32x4*)(Bb + i4 * 4);
                const f32x4 bx1 = *(const f32x4*)(Bb + 64 + i4 * 4);
                const f32x4 bu  = *(const f32x4*)(Bb + 128 + i4 * 4);
                const f32x4 bv  = *(const f32x4*)(Bb + 192 + i4 * 4);
                const f32x4 Pa = __builtin_elementwise_max(au * Ua4, av * Va4);
                const f32x4 Pb = __builtin_elementwise_max(bu * Ub4, bv * Vb4);
                Sa += Pa; A0a += Pa * ax0; A1a += Pa * ax1;
                Sb += Pb; A0b += Pb * bx0; A1b += Pb * bx1;
            }
            #pragma unroll
            for (int q = 0; q < 2; ++q) {
                const int t = ta + q;
                const f32x4 S4  = q ? Sb : Sa;
                const f32x4 A04 = q ? A0b : A0a;
                const f32x4 A14 = q ? A1b : A1a;
                const float pS = fmaxf(us[t] * Us[t], vs[t] * Vs[t]);   // self term, exact
                const float S  = (S4[0] + S4[1]) + (S4[2] + S4[3]) - pS;
                const float A0 = (A04[0] + A04[1]) + (A04[2] + A04[3]) - pS * x0s[t];
                const float A1 = (A14[0] + A14[1]) + (A14[2] + A14[3]) - pS * x1s[t];
                const float rs = 1.0f / S;
                const float h0 = (Wg00 * A0 + Wg01 * A1) * rs;
                const float h1 = (Wg10 * A0 + Wg11 * A1) * rs;
                const float h2 = (Wg20 * A0 + Wg21 * A1) * rs;
                const float h3 = (Wg30 * A0 + Wg31 * A1) * rs;
                const int lr = wv * 4 + t;
                const int hidx = (lr * 256 + lane * 4) ^ SWZ(lr);
                const uint2 hp = make_uint2(pack2bf(h0, h1), pack2bf(h2, h3));
                *(uint2*)(&h_lds[hidx]) = hp;
                if (MODE == 1) diag_h[(size_t)(base + lr) * 64 + lane] = hp;
            }
        }
    } else {
        // MODE 2: synthetic h_lds (garbage but safe bf16 patterns), no attention
        unsigned int* hw = (unsigned int*)h_lds;
        #pragma unroll
        for (int idx = 0; idx < 8; ++idx) {
            const int j = idx * 256 + tid;       // 0..2047
            const unsigned int lo = 0x3C00u | ((j * 13u) & 0xFFu);
            const unsigned int hi = 0x3C00u | ((j * 7u) & 0xFFu);
            hw[j] = lo | (hi << 16);
        }
    }
    if (MODE == 1) return;
    __syncthreads();

    // ================= conv (as matmul, K=256): fb = wv, wv+4 =================
    f32x4 accc[2];
    accc[0] = (f32x4){0.f, 0.f, 0.f, 0.f};
    accc[1] = (f32x4){0.f, 0.f, 0.f, 0.f};
    #pragma unroll
    for (int kc = 0; kc < 8; ++kc) {
        const bf16x8 hf  = *(const bf16x8*)(&h_lds[(r * 256 + kc * 32 + g * 8) ^ SWZ(r)]);
        const bf16x8 wfa = *(const bf16x8*)(wcv + (wv * 16 + r) * 256 + kc * 32 + g * 8);
        const bf16x8 wfb = *(const bf16x8*)(wcv + ((wv + 4) * 16 + r) * 256 + kc * 32 + g * 8);
        accc[0] = __builtin_amdgcn_mfma_f32_16x16x32_bf16(wfa, hf, accc[0], 0, 0, 0);
        accc[1] = __builtin_amdgcn_mfma_f32_16x16x32_bf16(wfb, hf, accc[1], 0, 0, 0);
    }
    #pragma unroll
    for (int q = 0; q < 2; ++q) {
        const int f0 = (wv + q * 4) * 16 + g * 4;
        const float4 bs = *(const float4*)(biasf + f0);
        const float v0 = accc[q][0] + bs.x, v1 = accc[q][1] + bs.y;
        const float v2 = accc[q][2] + bs.z, v3 = accc[q][3] + bs.w;
        *(float4*)(enc_out + (size_t)(base + r) * 128 + f0) = make_float4(v0, v1, v2, v3);
        const int fidx = (r * 128 + f0) ^ SWZ(r);
        *(uint2*)(&flat_lds[fidx]) = make_uint2(pack2bf(v0, v1), pack2bf(v2, v3));
    }
    __syncthreads();

    // ================= decoder layer1: 128 -> 512, relu; nb = 8wv..8wv+7 =================
    bf16x8 ff1[4];
    #pragma unroll
    for (int kb = 0; kb < 4; ++kb)
        ff1[kb] = *(const bf16x8*)(&flat_lds[(r * 128 + kb * 32 + g * 8) ^ SWZ(r)]);
    #pragma unroll
    for (int t = 0; t < 8; ++t) {
        const int nb = wv * 8 + t;
        f32x4 a1 = (f32x4){0.f, 0.f, 0.f, 0.f};
        #pragma unroll
        for (int kb = 0; kb < 4; ++kb) {
            const bf16x8 wf = *(const bf16x8*)(w1b + (nb * 16 + r) * 128 + kb * 32 + g * 8);
            a1 = __builtin_amdgcn_mfma_f32_16x16x32_bf16(wf, ff1[kb], a1, 0, 0, 0);
        }
        const int n0 = nb * 16 + g * 4;
        const float4 bs = *(const float4*)(b1 + n0);
        const float v0 = fmaxf(a1[0] + bs.x, 0.f);
        const float v1 = fmaxf(a1[1] + bs.y, 0.f);
        const float v2 = fmaxf(a1[2] + bs.z, 0.f);
        const float v3 = fmaxf(a1[3] + bs.w, 0.f);
        const int hdidx = (r * 512 + n0) ^ SWZ(r);
        *(uint2*)(&hdec_lds[hdidx]) = make_uint2(pack2bf(v0, v1), pack2bf(v2, v3));
    }
    __syncthreads();

    // ================= decoder layer2: 512 -> 128; mb = wv, wv+4 =================
    f32x4 acc2[2];
    acc2[0] = (f32x4){0.f, 0.f, 0.f, 0.f};
    acc2[1] = (f32x4){0.f, 0.f, 0.f, 0.f};
    #pragma unroll
    for (int np = 0; np < 16; ++np) {
        const bf16x8 hfd = *(const bf16x8*)(&hdec_lds[(r * 512 + np * 32 + g * 8) ^ SWZ(r)]);
        const bf16x8 wfa = *(const bf16x8*)(w2b + (wv * 16 + r) * 512 + np * 32 + g * 8);
        const bf16x8 wfb = *(const bf16x8*)(w2b + ((wv + 4) * 16 + r) * 512 + np * 32 + g * 8);
        acc2[0] = __builtin_amdgcn_mfma_f32_16x16x32_bf16(wfa, hfd, acc2[0], 0, 0, 0);
        acc2[1] = __builtin_amdgcn_mfma_f32_16x16x32_bf16(wfb, hfd, acc2[1], 0, 0, 0);
    }
    #pragma unroll
    for (int q = 0; q < 2; ++q) {
        const int m0 = (wv + q * 4) * 16 + g * 4;
        const float4 bs = *(const float4*)(b2 + m0);
        *(float4*)(dec_out + (size_t)(base + r) * 128 + m0) =
            make_float4(acc2[q][0] + bs.x, acc2[q][1] + bs.y,
                        acc2[q][2] + bs.z, acc2[q][3] + bs.w);
    }
}

extern "C" void kernel_launch(void* const* d_in, const int* in_sizes, int n_in,
                              void* d_out, int out_size, void* d_ws, size_t ws_size,
                              hipStream_t stream) {
    const float* x      = (const float*)d_in[0];
    const float* W_gat  = (const float*)d_in[1];
    const float* a_attn = (const float*)d_in[2];
    const float* conv_w = (const float*)d_in[3];
    const float* conv_b = (const float*)d_in[4];
    const float* dec_w1 = (const float*)d_in[5];
    const float* dec_b1 = (const float*)d_in[6];
    const float* dec_w2 = (const float*)d_in[7];
    const float* dec_b2 = (const float*)d_in[8];
    float* out = (float*)d_out;

    const int B = in_sizes[0] / 128;                 // 16384
    unsigned short* w1b = (unsigned short*)d_ws;     // 512*128
    unsigned short* w2b = w1b + 512 * 128;           // 128*512
    unsigned short* wcv = w2b + 128 * 512;           // 128*256
    float* biasf = (float*)(wcv + 128 * 256);        // 128

    // diagnostic scratch (only used if ws is big enough)
    char* wsb = (char*)d_ws;
    uint2* diag_h   = (uint2*)(wsb + (1u << 20));            // 8 MB
    float* diag_enc = (float*)(wsb + (9u << 20));            // 8 MB
    float* diag_dec = (float*)(wsb + (17u << 20));           // 8 MB
    const bool do_diag = ws_size >= (26u << 20);

    k0_prep<<<256, 256, 0, stream>>>(dec_w1, dec_w2, conv_w, conv_b, w1b, w2b, wcv, biasf);

    // real output
    k_fused<0><<<B / 16, 256, 0, stream>>>(x, W_gat, a_attn, w1b, w2b, wcv, biasf,
                                           dec_b1, dec_b2, out, out + (size_t)B * 128,
                                           diag_h);
    if (do_diag) {
        // attention-only
        k_fused<1><<<B / 16, 256, 0, stream>>>(x, W_gat, a_attn, w1b, w2b, wcv, biasf,
                                               dec_b1, dec_b2, diag_enc, diag_dec, diag_h);
        // MFMA-only
        k_fused<2><<<B / 16, 256, 0, stream>>>(x, W_gat, a_attn, w1b, w2b, wcv, biasf,
                                               dec_b1, dec_b2, diag_enc, diag_dec, diag_h);
    }
}

// Round 14
// 91.503 us; speedup vs baseline: 1.1705x; 1.1705x over previous
//
#include <hip/hip_runtime.h>

// ConvAutoEncoder: B=16384, T=64, C=2, D=4
// out = [encoder_out (B*128 f32) | decoded (B*128 f32)]
// R7 structure; attention staging packed to bf16 pairs: (x0,x1) and (u,v) as uint32.
// One ds_read_b128 = 4 neighbors of one array -> 32 LDS reads/row (was 64).

typedef __attribute__((ext_vector_type(8))) short bf16x8;
typedef __attribute__((ext_vector_type(4))) float f32x4;

__device__ __forceinline__ unsigned short f2bf(float f) {
    unsigned int u = __builtin_bit_cast(unsigned int, f);
    return (unsigned short)((u + 0x7FFFu + ((u >> 16) & 1u)) >> 16);
}
__device__ __forceinline__ unsigned int pack2bf(float a, float b) {
    return (unsigned int)f2bf(a) | ((unsigned int)f2bf(b) << 16);
}
__device__ __forceinline__ float bf_lo(unsigned int p) {   // low bf16 -> f32
    return __builtin_bit_cast(float, p << 16);
}
__device__ __forceinline__ float bf_hi(unsigned int p) {   // high bf16 -> f32
    return __builtin_bit_cast(float, p & 0xFFFF0000u);
}

#define SWZ(row) (((row) & 7) << 3)   // ushort-index XOR == byte XOR ((row&7)<<4)

// ---------------- kernel 0: weight prep ----------------
__global__ void k0_prep(const float* __restrict__ w1, const float* __restrict__ w2,
                        const float* __restrict__ cw, const float* __restrict__ cb,
                        unsigned short* __restrict__ w1b, unsigned short* __restrict__ w2b,
                        unsigned short* __restrict__ wcv, float* __restrict__ biasf) {
    int i = blockIdx.x * 256 + threadIdx.x;      // 0..65535
    if (i < 512 * 128) { w1b[i] = f2bf(w1[i]); w2b[i] = f2bf(w2[i]); }
    if (i < 128 * 256) {
        int f = i >> 8, kd = i & 255;            // f = 2*o + s, kd = node*4 + d
        int o = f >> 1, s = f & 1, node = kd >> 2, d = kd & 3;
        int k = d - s;
        float v = (k >= 0 && k < 3) ? cw[o * 192 + node * 3 + k] : 0.f;
        wcv[i] = f2bf(v);
    }
    if (i < 128) biasf[i] = cb[i >> 1];
}

// ---------------- fused kernel ----------------
// 4 waves, 16 batches/block. Attention: wave wv rows 4wv..4wv+3, bf16-packed staging,
// 2 interleaved row streams. Conv: fb={wv,wv+4}. L1: nb=8wv..8wv+7. L2: mb={wv,wv+4}.
__global__ __launch_bounds__(256, 4) void k_fused(
    const float* __restrict__ x,             // (B,64,2)
    const float* __restrict__ W_gat,         // (4,2)
    const float* __restrict__ a_attn,        // (8,)
    const unsigned short* __restrict__ w1b,  // (512,128)
    const unsigned short* __restrict__ w2b,  // (128,512)
    const unsigned short* __restrict__ wcv,  // (128,256)
    const float* __restrict__ biasf,         // (128,)
    const float* __restrict__ b1,            // (512,)
    const float* __restrict__ b2,            // (128,)
    float* __restrict__ enc_out,             // (B,128) f32
    float* __restrict__ dec_out)             // (B,128) f32
{
    __shared__ __align__(16) unsigned char smem[28672];
    unsigned short* h_lds    = (unsigned short*)smem;            // [16][256] bf16 swz, 8KB
    unsigned short* flat_lds = (unsigned short*)(smem + 8192);   // [16][128] bf16 swz, 4KB
    unsigned int*   scr      = (unsigned int*)(smem + 12288);    // [4 wv][4 rows][128]u32, 8KB } aliased
    unsigned short* hdec_lds = (unsigned short*)(smem + 12288);  // [16][512] bf16 swz, 16KB   }

    const int tid = threadIdx.x, lane = tid & 63, wv = tid >> 6;  // wv 0..3
    const int r = lane & 15, g = lane >> 4;
    const int base = blockIdx.x * 16;

    // ================= attention (4 rows per wave, bf16-packed staging) ==============
    {
        const float Wg00 = W_gat[0], Wg01 = W_gat[1], Wg10 = W_gat[2], Wg11 = W_gat[3];
        const float Wg20 = W_gat[4], Wg21 = W_gat[5], Wg30 = W_gat[6], Wg31 = W_gat[7];
        const float as0 = a_attn[0], as1 = a_attn[1], as2 = a_attn[2], as3 = a_attn[3];
        const float ad0 = a_attn[4], ad1 = a_attn[5], ad2 = a_attn[6], ad3 = a_attn[7];
        const float cs0 = as0 * Wg00 + as1 * Wg10 + as2 * Wg20 + as3 * Wg30;
        const float cs1 = as0 * Wg01 + as1 * Wg11 + as2 * Wg21 + as3 * Wg31;
        const float cd0 = ad0 * Wg00 + ad1 * Wg10 + ad2 * Wg20 + ad3 * Wg30;
        const float cd1 = ad0 * Wg01 + ad1 * Wg11 + ad2 * Wg21 + ad3 * Wg31;
        const float L2E = 1.4426950408889634f;
        const float SL = 0.2f;

        unsigned int* wbuf = scr + wv * 512;    // 4 rows x (64 xy | 64 uv) u32
        unsigned int xyps[4], uvps[4];
        float Us[4], Vs[4];

        #pragma unroll
        for (int t = 0; t < 4; ++t) {
            const float2 xv = ((const float2*)x)[(size_t)(base + wv * 4 + t) * 64 + lane];
            const float x0 = xv.x, x1 = xv.y;
            const float es = x0 * cs0 + x1 * cs1;
            const float ed = x0 * cd0 + x1 * cd1;
            const float u = __builtin_amdgcn_exp2f(es * L2E);         // e^{es}
            const float v = __builtin_amdgcn_exp2f(es * (SL * L2E));  // e^{0.2 es}
            const unsigned int xyp = pack2bf(x0, x1);
            const unsigned int uvp = pack2bf(u, v);
            wbuf[t * 128 + lane]      = xyp;
            wbuf[t * 128 + 64 + lane] = uvp;
            xyps[t] = xyp; uvps[t] = uvp;
            Us[t] = __builtin_amdgcn_exp2f(ed * L2E);
            Vs[t] = __builtin_amdgcn_exp2f(ed * (SL * L2E));
        }

        #pragma unroll
        for (int tp = 0; tp < 2; ++tp) {      // two rows interleaved -> 2 streams
            const int ta = tp * 2, tb = ta + 1;
            const uint4* xa = (const uint4*)(wbuf + ta * 128);
            const uint4* ua = (const uint4*)(wbuf + ta * 128 + 64);
            const uint4* xb = (const uint4*)(wbuf + tb * 128);
            const uint4* ub = (const uint4*)(wbuf + tb * 128 + 64);
            const float Ua = Us[ta], Va = Vs[ta];
            const float Ub = Us[tb], Vb = Vs[tb];
            float Sa0 = 0.f, Sa1 = 0.f, A0a0 = 0.f, A0a1 = 0.f, A1a0 = 0.f, A1a1 = 0.f;
            float Sb0 = 0.f, Sb1 = 0.f, A0b0 = 0.f, A0b1 = 0.f, A1b0 = 0.f, A1b1 = 0.f;
            #pragma unroll
            for (int i4 = 0; i4 < 16; ++i4) {
                const uint4 pxa = xa[i4];
                const uint4 pua = ua[i4];
                const uint4 pxb = xb[i4];
                const uint4 pub = ub[i4];
                {
                    const float P0 = fmaxf(bf_lo(pua.x) * Ua, bf_hi(pua.x) * Va);
                    const float P1 = fmaxf(bf_lo(pua.y) * Ua, bf_hi(pua.y) * Va);
                    const float P2 = fmaxf(bf_lo(pua.z) * Ua, bf_hi(pua.z) * Va);
                    const float P3 = fmaxf(bf_lo(pua.w) * Ua, bf_hi(pua.w) * Va);
                    Sa0 += P0; Sa1 += P1; Sa0 += P2; Sa1 += P3;
                    A0a0 += P0 * bf_lo(pxa.x); A1a0 += P0 * bf_hi(pxa.x);
                    A0a1 += P1 * bf_lo(pxa.y); A1a1 += P1 * bf_hi(pxa.y);
                    A0a0 += P2 * bf_lo(pxa.z); A1a0 += P2 * bf_hi(pxa.z);
                    A0a1 += P3 * bf_lo(pxa.w); A1a1 += P3 * bf_hi(pxa.w);
                }
                {
                    const float P0 = fmaxf(bf_lo(pub.x) * Ub, bf_hi(pub.x) * Vb);
                    const float P1 = fmaxf(bf_lo(pub.y) * Ub, bf_hi(pub.y) * Vb);
                    const float P2 = fmaxf(bf_lo(pub.z) * Ub, bf_hi(pub.z) * Vb);
                    const float P3 = fmaxf(bf_lo(pub.w) * Ub, bf_hi(pub.w) * Vb);
                    Sb0 += P0; Sb1 += P1; Sb0 += P2; Sb1 += P3;
                    A0b0 += P0 * bf_lo(pxb.x); A1b0 += P0 * bf_hi(pxb.x);
                    A0b1 += P1 * bf_lo(pxb.y); A1b1 += P1 * bf_hi(pxb.y);
                    A0b0 += P2 * bf_lo(pxb.z); A1b0 += P2 * bf_hi(pxb.z);
                    A0b1 += P3 * bf_lo(pxb.w); A1b1 += P3 * bf_hi(pxb.w);
                }
            }
            #pragma unroll
            for (int q = 0; q < 2; ++q) {
                const int t = ta + q;
                // self term: identical expression to the in-loop i==j term -> exact cancel
                const float ub_ = bf_lo(uvps[t]), vb_ = bf_hi(uvps[t]);
                const float x0b = bf_lo(xyps[t]), x1b = bf_hi(xyps[t]);
                const float Ut = Us[t], Vt = Vs[t];
                const float pS = fmaxf(ub_ * Ut, vb_ * Vt);
                const float S  = (q ? (Sb0 + Sb1) : (Sa0 + Sa1)) - pS;
                const float A0 = (q ? (A0b0 + A0b1) : (A0a0 + A0a1)) - pS * x0b;
                const float A1 = (q ? (A1b0 + A1b1) : (A1a0 + A1a1)) - pS * x1b;
                const float rs = 1.0f / S;
                const float h0 = (Wg00 * A0 + Wg01 * A1) * rs;
                const float h1 = (Wg10 * A0 + Wg11 * A1) * rs;
                const float h2 = (Wg20 * A0 + Wg21 * A1) * rs;
                const float h3 = (Wg30 * A0 + Wg31 * A1) * rs;
                const int lr = wv * 4 + t;
                const int hidx = (lr * 256 + lane * 4) ^ SWZ(lr);
                *(uint2*)(&h_lds[hidx]) = make_uint2(pack2bf(h0, h1), pack2bf(h2, h3));
            }
        }
    }
    __syncthreads();

    // ================= conv (as matmul, K=256): fb = wv, wv+4 =================
    f32x4 accc[2];
    accc[0] = (f32x4){0.f, 0.f, 0.f, 0.f};
    accc[1] = (f32x4){0.f, 0.f, 0.f, 0.f};
    #pragma unroll
    for (int kc = 0; kc < 8; ++kc) {
        const bf16x8 hf  = *(const bf16x8*)(&h_lds[(r * 256 + kc * 32 + g * 8) ^ SWZ(r)]);
        const bf16x8 wfa = *(const bf16x8*)(wcv + (wv * 16 + r) * 256 + kc * 32 + g * 8);
        const bf16x8 wfb = *(const bf16x8*)(wcv + ((wv + 4) * 16 + r) * 256 + kc * 32 + g * 8);
        accc[0] = __builtin_amdgcn_mfma_f32_16x16x32_bf16(wfa, hf, accc[0], 0, 0, 0);
        accc[1] = __builtin_amdgcn_mfma_f32_16x16x32_bf16(wfb, hf, accc[1], 0, 0, 0);
    }
    #pragma unroll
    for (int q = 0; q < 2; ++q) {
        const int f0 = (wv + q * 4) * 16 + g * 4;
        const float4 bs = *(const float4*)(biasf + f0);
        const float v0 = accc[q][0] + bs.x, v1 = accc[q][1] + bs.y;
        const float v2 = accc[q][2] + bs.z, v3 = accc[q][3] + bs.w;
        *(float4*)(enc_out + (size_t)(base + r) * 128 + f0) = make_float4(v0, v1, v2, v3);
        const int fidx = (r * 128 + f0) ^ SWZ(r);
        *(uint2*)(&flat_lds[fidx]) = make_uint2(pack2bf(v0, v1), pack2bf(v2, v3));
    }
    __syncthreads();

    // ================= decoder layer1: 128 -> 512, relu; nb = 8wv..8wv+7 =================
    bf16x8 ff1[4];
    #pragma unroll
    for (int kb = 0; kb < 4; ++kb)
        ff1[kb] = *(const bf16x8*)(&flat_lds[(r * 128 + kb * 32 + g * 8) ^ SWZ(r)]);
    #pragma unroll
    for (int t = 0; t < 8; ++t) {
        const int nb = wv * 8 + t;
        f32x4 a1 = (f32x4){0.f, 0.f, 0.f, 0.f};
        #pragma unroll
        for (int kb = 0; kb < 4; ++kb) {
            const bf16x8 wf = *(const bf16x8*)(w1b + (nb * 16 + r) * 128 + kb * 32 + g * 8);
            a1 = __builtin_amdgcn_mfma_f32_16x16x32_bf16(wf, ff1[kb], a1, 0, 0, 0);
        }
        const int n0 = nb * 16 + g * 4;
        const float4 bs = *(const float4*)(b1 + n0);
        const float v0 = fmaxf(a1[0] + bs.x, 0.f);
        const float v1 = fmaxf(a1[1] + bs.y, 0.f);
        const float v2 = fmaxf(a1[2] + bs.z, 0.f);
        const float v3 = fmaxf(a1[3] + bs.w, 0.f);
        const int hdidx = (r * 512 + n0) ^ SWZ(r);
        *(uint2*)(&hdec_lds[hdidx]) = make_uint2(pack2bf(v0, v1), pack2bf(v2, v3));
    }
    __syncthreads();

    // ================= decoder layer2: 512 -> 128; mb = wv, wv+4 =================
    f32x4 acc2[2];
    acc2[0] = (f32x4){0.f, 0.f, 0.f, 0.f};
    acc2[1] = (f32x4){0.f, 0.f, 0.f, 0.f};
    #pragma unroll
    for (int np = 0; np < 16; ++np) {
        const bf16x8 hfd = *(const bf16x8*)(&hdec_lds[(r * 512 + np * 32 + g * 8) ^ SWZ(r)]);
        const bf16x8 wfa = *(const bf16x8*)(w2b + (wv * 16 + r) * 512 + np * 32 + g * 8);
        const bf16x8 wfb = *(const bf16x8*)(w2b + ((wv + 4) * 16 + r) * 512 + np * 32 + g * 8);
        acc2[0] = __builtin_amdgcn_mfma_f32_16x16x32_bf16(wfa, hfd, acc2[0], 0, 0, 0);
        acc2[1] = __builtin_amdgcn_mfma_f32_16x16x32_bf16(wfb, hfd, acc2[1], 0, 0, 0);
    }
    #pragma unroll
    for (int q = 0; q < 2; ++q) {
        const int m0 = (wv + q * 4) * 16 + g * 4;
        const float4 bs = *(const float4*)(b2 + m0);
        *(float4*)(dec_out + (size_t)(base + r) * 128 + m0) =
            make_float4(acc2[q][0] + bs.x, acc2[q][1] + bs.y,
                        acc2[q][2] + bs.z, acc2[q][3] + bs.w);
    }
}

extern "C" void kernel_launch(void* const* d_in, const int* in_sizes, int n_in,
                              void* d_out, int out_size, void* d_ws, size_t ws_size,
                              hipStream_t stream) {
    const float* x      = (const float*)d_in[0];
    const float* W_gat  = (const float*)d_in[1];
    const float* a_attn = (const float*)d_in[2];
    const float* conv_w = (const float*)d_in[3];
    const float* conv_b = (const float*)d_in[4];
    const float* dec_w1 = (const float*)d_in[5];
    const float* dec_b1 = (const float*)d_in[6];
    const float* dec_w2 = (const float*)d_in[7];
    const float* dec_b2 = (const float*)d_in[8];
    float* out = (float*)d_out;

    const int B = in_sizes[0] / 128;                 // 16384
    unsigned short* w1b = (unsigned short*)d_ws;     // 512*128
    unsigned short* w2b = w1b + 512 * 128;           // 128*512
    unsigned short* wcv = w2b + 128 * 512;           // 128*256
    float* biasf = (float*)(wcv + 128 * 256);        // 128

    k0_prep<<<256, 256, 0, stream>>>(dec_w1, dec_w2, conv_w, conv_b, w1b, w2b, wcv, biasf);

    k_fused<<<B / 16, 256, 0, stream>>>(x, W_gat, a_attn, w1b, w2b, wcv, biasf,
                                        dec_b1, dec_b2, out, out + (size_t)B * 128);
}

// Round 15
// 32.851 us; speedup vs baseline: 3.2604x; 2.7854x over previous
//
#include <hip/hip_runtime.h>

// ConvAutoEncoder: B=16384, T=64, C=2, D=4
// out = [encoder_out (B*128 f32) | decoded (B*128 f32)]
// R7 structure (best: 50.6us). Change: weights stored FRAGMENT-MAJOR so every MFMA
// weight load is base + lane*16B (single coalesced 1KB segment) instead of 16
// scattered 64B segments. k0_prep performs the permutation.

typedef __attribute__((ext_vector_type(8))) short bf16x8;
typedef __attribute__((ext_vector_type(4))) float f32x4;

__device__ __forceinline__ unsigned short f2bf(float f) {
    unsigned int u = __builtin_bit_cast(unsigned int, f);
    return (unsigned short)((u + 0x7FFFu + ((u >> 16) & 1u)) >> 16);
}
__device__ __forceinline__ unsigned int pack2bf(float a, float b) {
    return (unsigned int)f2bf(a) | ((unsigned int)f2bf(b) << 16);
}

#define SWZ(row) (((row) & 7) << 3)   // ushort-index XOR == byte XOR ((row&7)<<4)

// ---------------- kernel 0: weight prep (fragment-major permutation) ----------------
// Fragment layout: frag*512 + lane*8 + e, lane = g*16+r, fragment covers rows
// (blk*16+r), cols (sub*32 + g*8 + e) of the logical weight matrix.
// w1c: frag = nb*4 + kb   (nb 0..31, kb 0..3)   from dec_w1 (512x128)
// w2c: frag = mb*16 + np  (mb 0..7,  np 0..15)  from dec_w2 (128x512)
// wcvc: frag = fb*8 + kc  (fb 0..7,  kc 0..7)   from conv-as-matmul (128x256)
__global__ void k0_prep(const float* __restrict__ w1, const float* __restrict__ w2,
                        const float* __restrict__ cw, const float* __restrict__ cb,
                        unsigned short* __restrict__ w1c, unsigned short* __restrict__ w2c,
                        unsigned short* __restrict__ wcvc, float* __restrict__ biasf) {
    const int i = blockIdx.x * 256 + threadIdx.x;      // 0..65535
    const int rem = i & 511, ln = rem >> 3, e = rem & 7;
    const int r = ln & 15, g = ln >> 4;
    {   // w1c (65536)
        const int frag = i >> 9, nb = frag >> 2, kb = frag & 3;
        w1c[i] = f2bf(w1[(nb * 16 + r) * 128 + kb * 32 + g * 8 + e]);
    }
    {   // w2c (65536)
        const int frag = i >> 9, mb = frag >> 4, np = frag & 15;
        w2c[i] = f2bf(w2[(mb * 16 + r) * 512 + np * 32 + g * 8 + e]);
    }
    if (i < 32768) {   // wcvc
        const int frag = i >> 9, fb = frag >> 3, kc = frag & 7;
        const int f = fb * 16 + r, kd = kc * 32 + g * 8 + e;
        const int o = f >> 1, s = f & 1, node = kd >> 2, d = kd & 3;
        const int k = d - s;
        const float v = (k >= 0 && k < 3) ? cw[o * 192 + node * 3 + k] : 0.f;
        wcvc[i] = f2bf(v);
    }
    if (i < 128) biasf[i] = cb[i >> 1];
}

// ---------------- fused kernel (R7, fragment-major weight loads) ----------------
// 4 waves, 16 batches/block. Attention: wave wv rows 4wv..4wv+3, per-row LDS buffers,
// 2-row interleaved accumulation. Conv: fb={wv,wv+4}. L1: nb=8wv..8wv+7. L2: mb={wv,wv+4}.
__global__ __launch_bounds__(256, 4) void k_fused(
    const float* __restrict__ x,             // (B,64,2)
    const float* __restrict__ W_gat,         // (4,2)
    const float* __restrict__ a_attn,        // (8,)
    const unsigned short* __restrict__ w1c,  // 128 frags x 512
    const unsigned short* __restrict__ w2c,  // 128 frags x 512
    const unsigned short* __restrict__ wcvc, // 64 frags x 512
    const float* __restrict__ biasf,         // (128,)
    const float* __restrict__ b1,            // (512,)
    const float* __restrict__ b2,            // (128,)
    float* __restrict__ enc_out,             // (B,128) f32
    float* __restrict__ dec_out)             // (B,128) f32
{
    __shared__ __align__(16) unsigned char smem[28672];
    unsigned short* h_lds    = (unsigned short*)smem;            // [16][256] bf16 swz, 8KB
    unsigned short* flat_lds = (unsigned short*)(smem + 8192);   // [16][128] bf16 swz, 4KB
    float*          scr      = (float*)(smem + 12288);           // [4 waves][4 rows][4][64], 16KB } aliased
    unsigned short* hdec_lds = (unsigned short*)(smem + 12288);  // [16][512] bf16 swz, 16KB      }

    const int tid = threadIdx.x, lane = tid & 63, wv = tid >> 6;  // wv 0..3
    const int r = lane & 15, g = lane >> 4;
    const int base = blockIdx.x * 16;
    const int l8 = lane * 8;

    // ================= attention (4 rows per wave) =================
    {
        const float Wg00 = W_gat[0], Wg01 = W_gat[1], Wg10 = W_gat[2], Wg11 = W_gat[3];
        const float Wg20 = W_gat[4], Wg21 = W_gat[5], Wg30 = W_gat[6], Wg31 = W_gat[7];
        const float as0 = a_attn[0], as1 = a_attn[1], as2 = a_attn[2], as3 = a_attn[3];
        const float ad0 = a_attn[4], ad1 = a_attn[5], ad2 = a_attn[6], ad3 = a_attn[7];
        const float cs0 = as0 * Wg00 + as1 * Wg10 + as2 * Wg20 + as3 * Wg30;
        const float cs1 = as0 * Wg01 + as1 * Wg11 + as2 * Wg21 + as3 * Wg31;
        const float cd0 = ad0 * Wg00 + ad1 * Wg10 + ad2 * Wg20 + ad3 * Wg30;
        const float cd1 = ad0 * Wg01 + ad1 * Wg11 + ad2 * Wg21 + ad3 * Wg31;
        const float L2E = 1.4426950408889634f;
        const float SL = 0.2f;

        float* wbuf = scr + wv * 1024;       // 4 rows x 256 floats (x0|x1|u|v)
        float x0s[4], x1s[4], us[4], vs[4], Us[4], Vs[4];

        #pragma unroll
        for (int t = 0; t < 4; ++t) {
            const float2 xv = ((const float2*)x)[(size_t)(base + wv * 4 + t) * 64 + lane];
            const float x0 = xv.x, x1 = xv.y;
            const float es = x0 * cs0 + x1 * cs1;
            const float ed = x0 * cd0 + x1 * cd1;
            const float u = __builtin_amdgcn_exp2f(es * L2E);         // e^{es}
            const float v = __builtin_amdgcn_exp2f(es * (SL * L2E));  // e^{0.2 es}
            const float U = __builtin_amdgcn_exp2f(ed * L2E);
            const float V = __builtin_amdgcn_exp2f(ed * (SL * L2E));
            float* Bf = wbuf + t * 256;
            Bf[lane] = x0; Bf[64 + lane] = x1; Bf[128 + lane] = u; Bf[192 + lane] = v;
            x0s[t] = x0; x1s[t] = x1; us[t] = u; vs[t] = v; Us[t] = U; Vs[t] = V;
        }

        #pragma unroll
        for (int tp = 0; tp < 2; ++tp) {      // two rows interleaved -> 2 streams
            const int ta = tp * 2, tb = ta + 1;
            const float* Ba = wbuf + ta * 256;
            const float* Bb = wbuf + tb * 256;
            const f32x4 Ua4 = {Us[ta], Us[ta], Us[ta], Us[ta]};
            const f32x4 Va4 = {Vs[ta], Vs[ta], Vs[ta], Vs[ta]};
            const f32x4 Ub4 = {Us[tb], Us[tb], Us[tb], Us[tb]};
            const f32x4 Vb4 = {Vs[tb], Vs[tb], Vs[tb], Vs[tb]};
            f32x4 Sa = {0.f, 0.f, 0.f, 0.f}, A0a = Sa, A1a = Sa;
            f32x4 Sb = Sa, A0b = Sa, A1b = Sa;
            #pragma unroll
            for (int i4 = 0; i4 < 16; ++i4) {
                const f32x4 ax0 = *(const f32x4*)(Ba + i4 * 4);
                const f32x4 ax1 = *(const f32x4*)(Ba + 64 + i4 * 4);
                const f32x4 au  = *(const f32x4*)(Ba + 128 + i4 * 4);
                const f32x4 av  = *(const f32x4*)(Ba + 192 + i4 * 4);
                const f32x4 bx0 = *(const f32x4*)(Bb + i4 * 4);
                const f32x4 bx1 = *(const f32x4*)(Bb + 64 + i4 * 4);
                const f32x4 bu  = *(const f32x4*)(Bb + 128 + i4 * 4);
                const f32x4 bv  = *(const f32x4*)(Bb + 192 + i4 * 4);
                const f32x4 Pa = __builtin_elementwise_max(au * Ua4, av * Va4);
                const f32x4 Pb = __builtin_elementwise_max(bu * Ub4, bv * Vb4);
                Sa += Pa; A0a += Pa * ax0; A1a += Pa * ax1;
                Sb += Pb; A0b += Pb * bx0; A1b += Pb * bx1;
            }
            #pragma unroll
            for (int q = 0; q < 2; ++q) {
                const int t = ta + q;
                const f32x4 S4  = q ? Sb : Sa;
                const f32x4 A04 = q ? A0b : A0a;
                const f32x4 A14 = q ? A1b : A1a;
                const float pS = fmaxf(us[t] * Us[t], vs[t] * Vs[t]);   // self term, exact
                const float S  = (S4[0] + S4[1]) + (S4[2] + S4[3]) - pS;
                const float A0 = (A04[0] + A04[1]) + (A04[2] + A04[3]) - pS * x0s[t];
                const float A1 = (A14[0] + A14[1]) + (A14[2] + A14[3]) - pS * x1s[t];
                const float rs = 1.0f / S;
                const float h0 = (Wg00 * A0 + Wg01 * A1) * rs;
                const float h1 = (Wg10 * A0 + Wg11 * A1) * rs;
                const float h2 = (Wg20 * A0 + Wg21 * A1) * rs;
                const float h3 = (Wg30 * A0 + Wg31 * A1) * rs;
                const int lr = wv * 4 + t;
                const int hidx = (lr * 256 + lane * 4) ^ SWZ(lr);
                *(uint2*)(&h_lds[hidx]) = make_uint2(pack2bf(h0, h1), pack2bf(h2, h3));
            }
        }
    }
    __syncthreads();

    // ================= conv (as matmul, K=256): fb = wv, wv+4 =================
    f32x4 accc[2];
    accc[0] = (f32x4){0.f, 0.f, 0.f, 0.f};
    accc[1] = (f32x4){0.f, 0.f, 0.f, 0.f};
    #pragma unroll
    for (int kc = 0; kc < 8; ++kc) {
        const bf16x8 hf  = *(const bf16x8*)(&h_lds[(r * 256 + kc * 32 + g * 8) ^ SWZ(r)]);
        const bf16x8 wfa = *(const bf16x8*)(wcvc + ((wv * 8 + kc) << 9) + l8);
        const bf16x8 wfb = *(const bf16x8*)(wcvc + (((wv + 4) * 8 + kc) << 9) + l8);
        accc[0] = __builtin_amdgcn_mfma_f32_16x16x32_bf16(wfa, hf, accc[0], 0, 0, 0);
        accc[1] = __builtin_amdgcn_mfma_f32_16x16x32_bf16(wfb, hf, accc[1], 0, 0, 0);
    }
    #pragma unroll
    for (int q = 0; q < 2; ++q) {
        const int f0 = (wv + q * 4) * 16 + g * 4;
        const float4 bs = *(const float4*)(biasf + f0);
        const float v0 = accc[q][0] + bs.x, v1 = accc[q][1] + bs.y;
        const float v2 = accc[q][2] + bs.z, v3 = accc[q][3] + bs.w;
        *(float4*)(enc_out + (size_t)(base + r) * 128 + f0) = make_float4(v0, v1, v2, v3);
        const int fidx = (r * 128 + f0) ^ SWZ(r);
        *(uint2*)(&flat_lds[fidx]) = make_uint2(pack2bf(v0, v1), pack2bf(v2, v3));
    }
    __syncthreads();

    // ================= decoder layer1: 128 -> 512, relu; nb = 8wv..8wv+7 =================
    bf16x8 ff1[4];
    #pragma unroll
    for (int kb = 0; kb < 4; ++kb)
        ff1[kb] = *(const bf16x8*)(&flat_lds[(r * 128 + kb * 32 + g * 8) ^ SWZ(r)]);
    #pragma unroll
    for (int t = 0; t < 8; ++t) {
        const int nb = wv * 8 + t;
        f32x4 a1 = (f32x4){0.f, 0.f, 0.f, 0.f};
        #pragma unroll
        for (int kb = 0; kb < 4; ++kb) {
            const bf16x8 wf = *(const bf16x8*)(w1c + (((nb << 2) + kb) << 9) + l8);
            a1 = __builtin_amdgcn_mfma_f32_16x16x32_bf16(wf, ff1[kb], a1, 0, 0, 0);
        }
        const int n0 = nb * 16 + g * 4;
        const float4 bs = *(const float4*)(b1 + n0);
        const float v0 = fmaxf(a1[0] + bs.x, 0.f);
        const float v1 = fmaxf(a1[1] + bs.y, 0.f);
        const float v2 = fmaxf(a1[2] + bs.z, 0.f);
        const float v3 = fmaxf(a1[3] + bs.w, 0.f);
        const int hdidx = (r * 512 + n0) ^ SWZ(r);
        *(uint2*)(&hdec_lds[hdidx]) = make_uint2(pack2bf(v0, v1), pack2bf(v2, v3));
    }
    __syncthreads();

    // ================= decoder layer2: 512 -> 128; mb = wv, wv+4 =================
    f32x4 acc2[2];
    acc2[0] = (f32x4){0.f, 0.f, 0.f, 0.f};
    acc2[1] = (f32x4){0.f, 0.f, 0.f, 0.f};
    #pragma unroll
    for (int np = 0; np < 16; ++np) {
        const bf16x8 hfd = *(const bf16x8*)(&hdec_lds[(r * 512 + np * 32 + g * 8) ^ SWZ(r)]);
        const bf16x8 wfa = *(const bf16x8*)(w2c + (((wv * 16) + np) << 9) + l8);
        const bf16x8 wfb = *(const bf16x8*)(w2c + ((((wv + 4) * 16) + np) << 9) + l8);
        acc2[0] = __builtin_amdgcn_mfma_f32_16x16x32_bf16(wfa, hfd, acc2[0], 0, 0, 0);
        acc2[1] = __builtin_amdgcn_mfma_f32_16x16x32_bf16(wfb, hfd, acc2[1], 0, 0, 0);
    }
    #pragma unroll
    for (int q = 0; q < 2; ++q) {
        const int m0 = (wv + q * 4) * 16 + g * 4;
        const float4 bs = *(const float4*)(b2 + m0);
        *(float4*)(dec_out + (size_t)(base + r) * 128 + m0) =
            make_float4(acc2[q][0] + bs.x, acc2[q][1] + bs.y,
                        acc2[q][2] + bs.z, acc2[q][3] + bs.w);
    }
}

extern "C" void kernel_launch(void* const* d_in, const int* in_sizes, int n_in,
                              void* d_out, int out_size, void* d_ws, size_t ws_size,
                              hipStream_t stream) {
    const float* x      = (const float*)d_in[0];
    const float* W_gat  = (const float*)d_in[1];
    const float* a_attn = (const float*)d_in[2];
    const float* conv_w = (const float*)d_in[3];
    const float* conv_b = (const float*)d_in[4];
    const float* dec_w1 = (const float*)d_in[5];
    const float* dec_b1 = (const float*)d_in[6];
    const float* dec_w2 = (const float*)d_in[7];
    const float* dec_b2 = (const float*)d_in[8];
    float* out = (float*)d_out;

    const int B = in_sizes[0] / 128;                 // 16384
    unsigned short* w1c  = (unsigned short*)d_ws;    // 128 frags x 512
    unsigned short* w2c  = w1c + 128 * 512;          // 128 frags x 512
    unsigned short* wcvc = w2c + 128 * 512;          // 64 frags x 512
    float* biasf = (float*)(wcvc + 64 * 512);        // 128

    k0_prep<<<256, 256, 0, stream>>>(dec_w1, dec_w2, conv_w, conv_b, w1c, w2c, wcvc, biasf);

    k_fused<<<B / 16, 256, 0, stream>>>(x, W_gat, a_attn, w1c, w2c, wcvc, biasf,
                                        dec_b1, dec_b2, out, out + (size_t)B * 128);
}